// Round 5
// baseline (261.098 us; speedup 1.0000x reference)
//
#include <hip/hip_runtime.h>
#include <math.h>

// GMM log-prob, S=1024 D=256 K=8 d=32. Target = dtype-faithful f32 numpy ref.
// Ref noise is dominated by f32 cov rounding amplified ~1e6-1e7x by near-ridge
// components. numpy's einsum sum_of_products_contig_outstride0_two compiles at
// BASELINE SIMD (not dispatched) = SSE3 on a pip wheel: vstep=4, no FMA
// (mul then add, separate roundings), 4x-unrolled REVERSED muladd chain,
// hadd reduce (l0+l1)+(l2+l3). We replicate that bitwise for cov, add the
// ridge in f32, then go f64 for Cholesky / triangular inverse / maha
// (zero-noise downstream beats an independent f32 noise draw).
// ws layout (doubles): Linv [2048*1024] | b [2048*32] | c [2048]  (~17.3 MB)

__global__ __launch_bounds__(64) void gmm_precompute(
    const float* __restrict__ mix,      // [256,8]
    const float* __restrict__ mean_p,   // [256,8,32]
    const float* __restrict__ cov_p,    // [256,8,32,32]
    const float* __restrict__ ds_stds,  // [256,32]
    double* __restrict__ LinvOut,       // [2048,32,32]
    double* __restrict__ bOut,          // [2048,32]
    double* __restrict__ cOut)          // [2048]
{
    const int pair = blockIdx.x;        // 0..2047
    const int dd   = pair >> 3;
    const int k    = pair & 7;
    const int t    = threadIdx.x;       // 0..63

    __shared__ float  Ws[1024];
    __shared__ double Cs[1024];
    __shared__ double Xd[1024];
    __shared__ double dl[32];
    __shared__ double hld;

    const float* wp = cov_p + (size_t)pair * 1024;
    for (int e = t; e < 1024; e += 64) Ws[e] = wp[e];
    __syncthreads();

    // cov in f32: numpy npyv-SSE3 baseline emulation.
    // products individually rounded; lanes l in [0,4):
    //   iter1: acc_l = p[l] + (p[4+l] + (p[8+l] + p[12+l]))
    //   iter2: acc_l = p[16+l] + (p[20+l] + (p[24+l] + (p[28+l] + acc_l)))
    // sum = (acc0+acc1) + (acc2+acc3); ridge +1e-5f in f32.
    for (int e = t; e < 1024; e += 64) {
        const int r = e >> 5, c = e & 31;
        if (c <= r) {
            const float* Wr = &Ws[r*32];
            const float* Wc = &Ws[c*32];
            float p[32];
            #pragma unroll
            for (int j = 0; j < 32; ++j)
                p[j] = __fmul_rn(Wr[j], Wc[j]);
            float acc[4];
            #pragma unroll
            for (int l = 0; l < 4; ++l) {
                float tchain = p[12+l];
                tchain = __fadd_rn(p[8+l],  tchain);
                tchain = __fadd_rn(p[4+l],  tchain);
                tchain = __fadd_rn(p[0+l],  tchain);
                float t2 = __fadd_rn(p[28+l], tchain);
                t2 = __fadd_rn(p[24+l], t2);
                t2 = __fadd_rn(p[20+l], t2);
                acc[l] = __fadd_rn(p[16+l], t2);
            }
            const float h0 = __fadd_rn(acc[0], acc[1]);
            const float h1 = __fadd_rn(acc[2], acc[3]);
            float s = __fadd_rn(h0, h1);
            if (r == c) s = __fadd_rn(s, 1.0e-5f);
            Cs[e] = (double)s;
        }
    }
    __syncthreads();

    // in-place Cholesky (lower), fp64
    for (int j = 0; j < 32; ++j) {
        if (t == 0) Cs[j*33] = sqrt(Cs[j*33]);
        __syncthreads();
        if (t > j && t < 32) Cs[t*32+j] /= Cs[j*33];
        __syncthreads();
        for (int e = t; e < 1024; e += 64) {
            const int r = e >> 5, c = e & 31;
            if (c <= r && c > j && r > j)
                Cs[e] -= Cs[r*32+j] * Cs[c*32+j];
        }
        __syncthreads();
    }

    // half_logdet
    if (t < 32) dl[t] = log(Cs[t*33]);
    __syncthreads();
    if (t == 0) {
        double s = 0.0;
        for (int j = 0; j < 32; ++j) s += dl[j];
        hld = s;
    }

    // triangular inverse: lane c owns column c of X = L^{-1}.
    if (t < 32) {
        const int c = t;
        double x[32];
        #pragma unroll
        for (int r = 0; r < 32; ++r) {
            double s = (r == c) ? 1.0 : 0.0;
            #pragma unroll
            for (int j = 0; j < r; ++j) s -= Cs[r*32+j] * x[j];
            x[r] = s / Cs[r*33];
        }
        #pragma unroll
        for (int r = 0; r < 32; ++r) Xd[r*32+c] = x[r];
    }
    __syncthreads();

    // write Linv (coalesced, f64)
    double* lp = LinvOut + (size_t)pair * 1024;
    for (int e = t; e < 1024; e += 64) lp[e] = Xd[e];

    // b = Linv * mu, f64
    const float* mup = mean_p + (size_t)pair * 32;
    if (t < 32) {
        double s = 0.0;
        for (int j = 0; j <= t; ++j) s += Xd[t*32+j] * (double)mup[j];
        bOut[(size_t)pair*32 + t] = s;
    }

    if (t == 0) {
        const float* mrow = mix + dd*8;
        double mx = (double)mrow[0];
        for (int q = 1; q < 8; ++q) mx = fmax(mx, (double)mrow[q]);
        double se = 0.0;
        for (int q = 0; q < 8; ++q) se += exp((double)mrow[q] - mx);
        const double logpi = (double)mrow[k] - mx - log(se);
        double sl = 0.0;
        const float* sp = ds_stds + dd*32;
        for (int j = 0; j < 32; ++j) sl += log((double)sp[j]);
        cOut[pair] = logpi - hld - 16.0*log(2.0*M_PI) - sl;
    }
}

// Heavy kernel: 512 blocks x 256 threads, one dd + 512 samples per block,
// 2 samples/thread. L,b,c staged f64 in LDS (66 KB).
__global__ __launch_bounds__(256, 2) void gmm_main(
    const float* __restrict__ data,     // [1024,256,32]
    const float* __restrict__ ds_means, // [256,32]
    const float* __restrict__ ds_stds,  // [256,32]
    const double* __restrict__ Linv,    // [2048,32,32]
    const double* __restrict__ bvec,    // [2048,32]
    const double* __restrict__ cdk,     // [2048]
    float* __restrict__ out)            // [1024,256]
{
    const int dd = blockIdx.x;          // 0..255
    const int sc = blockIdx.y;          // 0..1
    const int t  = threadIdx.x;

    __shared__ double Ls[8192];         // Linv[8][32][32], 64 KB
    __shared__ double bs[256];
    __shared__ double cs[8];
    __shared__ float  mn[32];
    __shared__ float  is[32];

    const double2* Lp = (const double2*)(Linv + (size_t)dd * 8192);
    double2* Ld = (double2*)Ls;
    for (int e = t; e < 4096; e += 256) Ld[e] = Lp[e];
    bs[t] = bvec[(size_t)dd*256 + t];
    if (t < 8)  cs[t] = cdk[dd*8 + t];
    if (t < 32) { mn[t] = ds_means[dd*32+t]; is[t] = ds_stds[dd*32+t]; }
    __syncthreads();

    const int s0 = sc*512 + t;
    const int s1 = s0 + 256;

    double y0[32], y1[32];
    const float4* x0 = (const float4*)(data + ((size_t)s0*256 + dd)*32);
    const float4* x1 = (const float4*)(data + ((size_t)s1*256 + dd)*32);
    #pragma unroll
    for (int q = 0; q < 8; ++q) {
        const float4 va = x0[q];
        const float4 vb = x1[q];
        const int j4 = 4*q;
        y0[j4+0] = ((double)va.x - (double)mn[j4+0]) / (double)is[j4+0];
        y0[j4+1] = ((double)va.y - (double)mn[j4+1]) / (double)is[j4+1];
        y0[j4+2] = ((double)va.z - (double)mn[j4+2]) / (double)is[j4+2];
        y0[j4+3] = ((double)va.w - (double)mn[j4+3]) / (double)is[j4+3];
        y1[j4+0] = ((double)vb.x - (double)mn[j4+0]) / (double)is[j4+0];
        y1[j4+1] = ((double)vb.y - (double)mn[j4+1]) / (double)is[j4+1];
        y1[j4+2] = ((double)vb.z - (double)mn[j4+2]) / (double)is[j4+2];
        y1[j4+3] = ((double)vb.w - (double)mn[j4+3]) / (double)is[j4+3];
    }

    float a0[8], a1[8];
    #pragma unroll 1
    for (int k = 0; k < 8; ++k) {
        double q00 = 0.0, q01 = 0.0, q10 = 0.0, q11 = 0.0;
        #pragma unroll 1
        for (int i = 0; i < 32; i += 2) {
            const double* L0 = &Ls[(k*32+i)*32];
            const double* L1 = L0 + 32;
            const double b0 = bs[k*32+i];
            const double b1 = bs[k*32+i+1];
            double z00 = -b0, z01 = -b1, z10 = -b0, z11 = -b1;
            #pragma unroll
            for (int j = 0; j < 32; ++j) {
                const double l0 = L0[j];
                const double l1 = L1[j];
                z00 = fma(l0, y0[j], z00);
                z10 = fma(l0, y1[j], z10);
                z01 = fma(l1, y0[j], z01);
                z11 = fma(l1, y1[j], z11);
            }
            q00 = fma(z00, z00, q00);
            q10 = fma(z10, z10, q10);
            q01 = fma(z01, z01, q01);
            q11 = fma(z11, z11, q11);
        }
        a0[k] = (float)(cs[k] - 0.5*(q00 + q01));
        a1[k] = (float)(cs[k] - 0.5*(q10 + q11));
    }

    float m0 = a0[0], m1 = a1[0];
    #pragma unroll
    for (int k = 1; k < 8; ++k) { m0 = fmaxf(m0, a0[k]); m1 = fmaxf(m1, a1[k]); }
    float e0 = 0.f, e1 = 0.f;
    #pragma unroll
    for (int k = 0; k < 8; ++k) { e0 += expf(a0[k]-m0); e1 += expf(a1[k]-m1); }
    out[(size_t)s0*256 + dd] = m0 + logf(e0);
    out[(size_t)s1*256 + dd] = m1 + logf(e1);
}

extern "C" void kernel_launch(void* const* d_in, const int* in_sizes, int n_in,
                              void* d_out, int out_size, void* d_ws, size_t ws_size,
                              hipStream_t stream) {
    const float* data   = (const float*)d_in[0];   // [1024,256,32]
    const float* mix    = (const float*)d_in[1];   // [256,8]
    const float* mean_p = (const float*)d_in[2];   // [256,8,32]
    const float* cov_p  = (const float*)d_in[3];   // [256,8,32,32]
    const float* ds_m   = (const float*)d_in[4];   // [256,32]
    const float* ds_s   = (const float*)d_in[5];   // [256,32]
    float* out = (float*)d_out;

    double* Linv = (double*)d_ws;               // 2048*1024 f64
    double* bvec = Linv + 2048*1024;            // 2048*32 f64
    double* cdk  = bvec + 2048*32;              // 2048 f64

    gmm_precompute<<<2048, 64, 0, stream>>>(mix, mean_p, cov_p, ds_s, Linv, bvec, cdk);
    dim3 grid(256, 2);
    gmm_main<<<grid, 256, 0, stream>>>(data, ds_m, ds_s, Linv, bvec, cdk, out);
}